// Round 6
// baseline (76.977 us; speedup 1.0000x reference)
//
#include <hip/hip_runtime.h>

// Barnes-Wall Lambda16 quantizer — mod-2 surrogate pass-1 (register-lean) +
// bit-exact pass-2 (R4-verified eval_k).
//
// Pass 1 (surrogate, per k): dd_j(k) ~= dd_{r}[j] where r = c_j(k) mod 2 —
// true in real arithmetic (rint commutes with integer shifts), off by
// ~2^-30-level rounding in f32 (binade effects), which is harmless for
// RANKING (top-3 margin validated on this dataset in R5, absmax 0.0).
//   Dtil_k = sum_j dd_sel^2 + par_k * (1 - 2*max_j|dd_sel|)  ( = D_k/4 )
// With k unrolled, the odd-mask O(k) and carry parity par2(k) are
// compile-time, so dd selection is static register naming (0 instructions).
// Parity: par = (popcount((P1&O)|(P0&~O)) + par2(k)) & 1 — validated R5.
// Keep stable top-3.
//
// Pass 2: bit-exact numpy pipeline eval_k (R2/R3/R4-verified; absmax 0.0
// across ~10M candidate evaluations) on the 3 survivors; winner by
// lexicographic (D,k) == numpy first-min; one emit eval for the winner.
// NOTE: pass-2 must NOT use the mod-2 tables — fl((x-c)/2) residuals are
// not bit-identical across c of equal parity (rounding-grid/binade shifts).
//
// Register discipline (R5 post-mortem: 112 persistent floats -> scratch,
// 234 MB HBM spill traffic): persistent set here is x[16]+dd0[16]+dd1[16]
// +P0,P1+top3 ~ 60 regs; amdgpu_waves_per_eu(4,4) pins the cap at 128 and
// disables the spill-for-occupancy heuristic (grid is 16 waves/CU anyway).
//
// Bit-exactness invariants for pass-2 (absmax must be 0.0):
//  - fp contract OFF; fmaf only where exact or single-rounding-identical:
//    fmaf(c,-0.5,xh) == fl(xh-c/2) == fl(fl(x-c)*0.5); fmaf(2,f,c) exact;
//    Xp = fmaf(bit,+-2,X) exact (integers).
//  - rintf == round-half-to-even == np.round; dd = x2 - f exact.
//  - first-max: contiguous-pair tournament, left wins ties (>=).
//  - corr = f + sign(dd) == ceil(xc)+floor(xc)-fc (incl. exact halves).
//  - e = Xp - x directly (single rounding); D in numpy's n=16 pairwise
//    order: r[j]=sq[j]+sq[j+8]; D=((r0+r1)+(r2+r3))+((r4+r5)+(r6+r7)).
//  - parity: float sum-tree of integer-valued f (exact), cvt, &1.

constexpr int G5[5][16] = {
    {1,1,1,1,0,1,0,1,1,0,0,1,0,0,0,0},
    {0,1,1,1,1,0,1,0,1,1,0,0,1,0,0,0},
    {0,0,1,1,1,1,0,1,0,1,1,0,0,1,0,0},
    {0,0,0,1,1,1,1,0,1,0,1,1,0,0,1,0},
    {1,1,1,1,1,1,1,1,1,1,1,1,1,1,1,1}};

struct Tab {
  int m[16];     // column bit-masks: c_j(k) = popcount(k & m[j])
  int odd[32];   // bit j = c_j(k) & 1  (GF(2)-linear in k)
  int par2[32];  // XOR_j ((c_j(k) >> 1) & 1)
};
constexpr Tab make_tab() {
  Tab t{};
  for (int j = 0; j < 16; ++j) {
    int m = 0;
    for (int i = 0; i < 5; ++i) m |= G5[i][j] << (4 - i);
    t.m[j] = m;
  }
  for (int k = 0; k < 32; ++k) {
    int om = 0, p2 = 0;
    for (int j = 0; j < 16; ++j) {
      int c = 0;
      for (int i = 0; i < 5; ++i) c += ((k >> (4 - i)) & 1) * G5[i][j];
      om |= (c & 1) << j;
      p2 ^= (c >> 1) & 1;
    }
    t.odd[k] = om;
    t.par2[k] = p2;
  }
  return t;
}
constexpr Tab tb = make_tab();

__device__ __forceinline__ int parity16i(const float (&f)[16]) {
  // exact: all addends are small integers
  float s0 = ((f[0] + f[1]) + (f[2] + f[3])) + ((f[4] + f[5]) + (f[6] + f[7]));
  float s1 = ((f[8] + f[9]) + (f[10] + f[11])) + ((f[12] + f[13]) + (f[14] + f[15]));
  return ((int)(s0 + s1)) & 1;
}

// Exact numpy-pipeline evaluation of candidate kk (R4-verified machinery).
template <bool EMIT>
__device__ __forceinline__ float eval_k(int kk, const float (&x)[16],
                                        const float (&xh)[16], float a,
                                        float (&y)[16]) {
#pragma clang fp contract(off)
  float f[16], dd[16];
#pragma unroll
  for (int j = 0; j < 16; ++j) {
    float c = (float)__builtin_popcount(kk & tb.m[j]);
    float x2 = __builtin_fmaf(c, -0.5f, xh[j]);  // == fl(xh - c/2)
    float fj = __builtin_rintf(x2);
    f[j] = fj;
    dd[j] = x2 - fj;                             // exact
  }
  const int par = parity16i(f);

  // first-occurrence argmax of |dd| -> onehot (left wins ties)
  float tv[16];
  int ti[16];
#pragma unroll
  for (int j = 0; j < 16; ++j) { tv[j] = __builtin_fabsf(dd[j]); ti[j] = 1 << j; }
#pragma unroll
  for (int w = 8; w >= 1; w >>= 1) {
#pragma unroll
    for (int j = 0; j < w; ++j) {
      bool L = tv[2 * j] >= tv[2 * j + 1];
      tv[j] = L ? tv[2 * j] : tv[2 * j + 1];
      ti[j] = L ? ti[2 * j] : ti[2 * j + 1];
    }
  }
  const int ohm = par ? ti[0] : 0;   // patch mask (0 when parity even)

  float sq[16];
#pragma unroll
  for (int j = 0; j < 16; ++j) {
    float c  = (float)__builtin_popcount(kk & tb.m[j]);
    float X  = __builtin_fmaf(2.0f, f[j], c);          // exact int
    float s2 = __builtin_copysignf(2.0f, dd[j]);       // corr direction
    float bitf = (float)((ohm >> j) & 1);
    float Xp = __builtin_fmaf(bitf, s2, X);            // exact int
    float e  = Xp - x[j];                              // single rounding
    sq[j] = e * e;
    if (EMIT) y[j] = Xp * a;
  }
  float r0 = sq[0] + sq[8],  r1 = sq[1] + sq[9];
  float r2 = sq[2] + sq[10], r3 = sq[3] + sq[11];
  float r4 = sq[4] + sq[12], r5 = sq[5] + sq[13];
  float r6 = sq[6] + sq[14], r7 = sq[7] + sq[15];
  return ((r0 + r1) + (r2 + r3)) + ((r4 + r5) + (r6 + r7));
}

__global__ __launch_bounds__(256)
__attribute__((amdgpu_waves_per_eu(4, 4)))
void bw_quant_kernel(
    const float* __restrict__ x_in,
    const float* __restrict__ C_rep,   // unused (constexpr codebook)
    const float* __restrict__ a_ptr,
    float* __restrict__ y_out,
    int n_rows)
{
#pragma clang fp contract(off)
  const int row = blockIdx.x * 256 + threadIdx.x;
  if (row >= n_rows) return;

  const float a = a_ptr[0];

  float x[16];
  {
    const float4* xr4 = reinterpret_cast<const float4*>(x_in + (size_t)row * 16);
#pragma unroll
    for (int q = 0; q < 4; ++q) {
      float4 v = xr4[q];
      x[q * 4 + 0] = v.x / a;
      x[q * 4 + 1] = v.y / a;
      x[q * 4 + 2] = v.z / a;
      x[q * 4 + 3] = v.w / a;
    }
  }

  // -------- per-coordinate mod-2 signed residual tables (pass-1 only) -----
  float dd0[16], dd1[16];
  int P0 = 0, P1 = 0;   // bit j = parity of rint(xh_j) / rint(xh_j - 0.5)
#pragma unroll
  for (int j = 0; j < 16; ++j) {
    float xh = x[j] * 0.5f;                 // exact
    float t0 = __builtin_rintf(xh);
    dd0[j] = xh - t0;
    float h  = xh - 0.5f;
    float t1 = __builtin_rintf(h);
    dd1[j] = h - t1;
    P0 |= ((int)t0 & 1) << j;
    P1 |= ((int)t1 & 1) << j;
  }

  // -------- pass 1: surrogate ranking, keep stable top-3 ------------------
  float b1 = __builtin_inff(), b2 = b1, b3 = b1;
  int k1 = 0, k2 = 0, k3 = 0;

#pragma unroll
  for (int k = 0; k < 32; ++k) {
    const unsigned O = (unsigned)tb.odd[k];   // compile-time constant
    const int     Pc = tb.par2[k];            // compile-time constant

    float dj[16];
#pragma unroll
    for (int j = 0; j < 16; ++j)
      dj[j] = ((O >> j) & 1u) ? dd1[j] : dd0[j];   // static register naming

    // ssum = sum dj^2 : 4 parallel fma chains (surrogate precision)
    float s0 = __builtin_fmaf(dj[0], dj[0], __builtin_fmaf(dj[1], dj[1],
               __builtin_fmaf(dj[2], dj[2], dj[3] * dj[3])));
    float s1 = __builtin_fmaf(dj[4], dj[4], __builtin_fmaf(dj[5], dj[5],
               __builtin_fmaf(dj[6], dj[6], dj[7] * dj[7])));
    float s2 = __builtin_fmaf(dj[8], dj[8], __builtin_fmaf(dj[9], dj[9],
               __builtin_fmaf(dj[10], dj[10], dj[11] * dj[11])));
    float s3 = __builtin_fmaf(dj[12], dj[12], __builtin_fmaf(dj[13], dj[13],
               __builtin_fmaf(dj[14], dj[14], dj[15] * dj[15])));
    float s = (s0 + s1) + (s2 + s3);

    // mx = max |dj| (abs folds into max source modifiers)
    float m01 = __builtin_fmaxf(__builtin_fabsf(dj[0]),  __builtin_fabsf(dj[1]));
    float m23 = __builtin_fmaxf(__builtin_fabsf(dj[2]),  __builtin_fabsf(dj[3]));
    float m45 = __builtin_fmaxf(__builtin_fabsf(dj[4]),  __builtin_fabsf(dj[5]));
    float m67 = __builtin_fmaxf(__builtin_fabsf(dj[6]),  __builtin_fabsf(dj[7]));
    float m89 = __builtin_fmaxf(__builtin_fabsf(dj[8]),  __builtin_fabsf(dj[9]));
    float mab = __builtin_fmaxf(__builtin_fabsf(dj[10]), __builtin_fabsf(dj[11]));
    float mcd = __builtin_fmaxf(__builtin_fabsf(dj[12]), __builtin_fabsf(dj[13]));
    float mef = __builtin_fmaxf(__builtin_fabsf(dj[14]), __builtin_fabsf(dj[15]));
    float mx = __builtin_fmaxf(
        __builtin_fmaxf(__builtin_fmaxf(m01, m23), __builtin_fmaxf(m45, m67)),
        __builtin_fmaxf(__builtin_fmaxf(m89, mab), __builtin_fmaxf(mcd, mef)));

    unsigned sel = (unsigned)((P1 & (int)O) | (P0 & ~(int)O));
    int par = (__builtin_popcount(sel) + Pc) & 1;
    float spen = s + __builtin_fmaf(-2.0f, mx, 1.0f);
    float dtil = par ? spen : s;

    // stable top-3 insert (strict <: earlier k wins ties)
    bool lt1 = dtil < b1, lt2 = dtil < b2, lt3 = dtil < b3;
    float nb3 = lt3 ? (lt2 ? b2 : dtil) : b3;  int nk3 = lt3 ? (lt2 ? k2 : k) : k3;
    float nb2 = lt2 ? (lt1 ? b1 : dtil) : b2;  int nk2 = lt2 ? (lt1 ? k1 : k) : k2;
    b3 = nb3; k3 = nk3;
    b2 = nb2; k2 = nk2;
    b1 = lt1 ? dtil : b1;  k1 = lt1 ? k : k1;
  }

  // -------- pass 2: exact evaluation of the 3 survivors -------------------
  float xh[16];
#pragma unroll
  for (int j = 0; j < 16; ++j) xh[j] = x[j] * 0.5f;   // exact

  float ydummy[16];
  float D1 = eval_k<false>(k1, x, xh, a, ydummy);
  float D2 = eval_k<false>(k2, x, xh, a, ydummy);
  float D3 = eval_k<false>(k3, x, xh, a, ydummy);

  // lexicographic (D, k) == numpy first-min over the candidate set
  bool c2 = (D2 < D1) || (D2 == D1 && k2 < k1);
  float Db = c2 ? D2 : D1;
  int kb = c2 ? k2 : k1;
  bool c3 = (D3 < Db) || (D3 == Db && k3 < kb);
  kb = c3 ? k3 : kb;

  // -------- emit: exact re-eval of the winner -----------------------------
  float y[16];
  (void)eval_k<true>(kb, x, xh, a, y);

  float4* yr4 = reinterpret_cast<float4*>(y_out + (size_t)row * 16);
#pragma unroll
  for (int q = 0; q < 4; ++q) {
    float4 v;
    v.x = y[q * 4 + 0]; v.y = y[q * 4 + 1];
    v.z = y[q * 4 + 2]; v.w = y[q * 4 + 3];
    yr4[q] = v;
  }
}

extern "C" void kernel_launch(void* const* d_in, const int* in_sizes, int n_in,
                              void* d_out, int out_size, void* d_ws, size_t ws_size,
                              hipStream_t stream) {
  const float* x_in  = (const float*)d_in[0];
  const float* C_rep = (const float*)d_in[1];
  const float* a_ptr = (const float*)d_in[2];
  float* y_out = (float*)d_out;

  const int n_rows = in_sizes[0] / 16;
  const int block = 256;
  const int grid = (n_rows + block - 1) / block;
  bw_quant_kernel<<<grid, block, 0, stream>>>(x_in, C_rep, a_ptr, y_out, n_rows);
}

// Round 7
// 36.426 us; speedup vs baseline: 2.1132x; 2.1132x over previous
//
#include <hip/hip_runtime.h>

// Barnes-Wall Lambda16 quantizer — R4 skeleton (rolled pass-1, launch_bounds
// (256,4), no spills) with: SMEM codebook rows (s_load_dwordx16 replaces 16
// ds_reads/k), mask-based surrogate parity (R5/R6-validated), v_max3 trees,
// top-3 filter (validated), bit-exact pass-2 (R2..R6-verified eval_k).
//
// Pass 1 (surrogate, rolled over k): dd_j = x2 - rint(x2), x2 = xh - ch[k][j];
//   Dtil_k = ssum + par_k * (1 - 2*mx)   ( = D_k/4 in reals )
// parity via bitmasks: par = (popcount((P1&O)|(P0&~O)) + par2(k)) & 1 where
// P0/P1 = per-coordinate parities of rint(xh)/rint(xh-0.5), O = odd-mask of
// codeword k, par2 = carry parity. Exactness of the mask parity vs the
// f-sum parity holds up to ~2^-24-probability binade effects — surrogate
// only affects RANKING; validated absmax 0.0 on this dataset in R5 and R6.
// Keep stable top-3 (validated R5/R6).
//
// Pass 2: bit-exact numpy pipeline eval_k on the 3 survivors; winner by
// lexicographic (D,k) == numpy first-min; one emit eval for the winner.
//
// Bit-exactness invariants for pass-2 (absmax must be 0.0):
//  - fp contract OFF; fmaf only where exact or single-rounding-identical:
//    fmaf(c,-0.5,xh) == fl(xh-c/2) == fl(fl(x-c)*0.5); fmaf(2,f,c) exact;
//    Xp = fmaf(bit,+-2,X) exact (integers).
//  - rintf == round-half-to-even == np.round; dd = x2 - f exact.
//  - first-max: contiguous-pair tournament, left wins ties (>=).
//  - corr = f + sign(dd) == ceil(xc)+floor(xc)-fc (incl. exact halves).
//  - e = Xp - x directly (single rounding); D in numpy's n=16 pairwise
//    order: r[j]=sq[j]+sq[j+8]; D=((r0+r1)+(r2+r3))+((r4+r5)+(r6+r7)).
//  - parity (pass-2): float sum-tree of integer-valued f (exact), cvt, &1.
//
// Register discipline (R5/R6 post-mortem): rolled pass-1, NO cross-iteration
// float tables; persistent set = x[16]+xh[16]+P0,P1+top3 ≈ 40 regs.
// __launch_bounds__(256,4) caps VGPR at 128 (R3 proved launch_bounds is
// honored; R6 proved amdgpu_waves_per_eu is not).

constexpr int G5[5][16] = {
    {1,1,1,1,0,1,0,1,1,0,0,1,0,0,0,0},
    {0,1,1,1,1,0,1,0,1,1,0,0,1,0,0,0},
    {0,0,1,1,1,1,0,1,0,1,1,0,0,1,0,0},
    {0,0,0,1,1,1,1,0,1,0,1,1,0,0,1,0},
    {1,1,1,1,1,1,1,1,1,1,1,1,1,1,1,1}};

struct Masks { int m[16]; };
constexpr Masks make_masks() {
  Masks mk{};
  for (int j = 0; j < 16; ++j) {
    int m = 0;
    for (int i = 0; i < 5; ++i) m |= G5[i][j] << (4 - i);
    mk.m[j] = m;
  }
  return mk;
}
constexpr Masks mk = make_masks();

// Per-candidate row: 16 half-codeword floats + odd-mask + carry-parity.
// 80B rows; k is wave-uniform in the rolled pass-1 loop -> s_load.
struct KRow { float ch[16]; unsigned odd; unsigned par2; unsigned pad0, pad1; };
struct KTab { KRow r[32]; };
constexpr KTab make_ktab() {
  KTab t{};
  for (int k = 0; k < 32; ++k) {
    unsigned om = 0, p2 = 0;
    for (int j = 0; j < 16; ++j) {
      int c = 0;
      for (int i = 0; i < 5; ++i) c += ((k >> (4 - i)) & 1) * G5[i][j];
      t.r[k].ch[j] = 0.5f * (float)c;   // exact
      om |= (unsigned)(c & 1) << j;
      p2 ^= (unsigned)((c >> 1) & 1);
    }
    t.r[k].odd = om;
    t.r[k].par2 = p2;
    t.r[k].pad0 = 0; t.r[k].pad1 = 0;
  }
  return t;
}
constexpr KTab ktab = make_ktab();

__device__ __forceinline__ int parity16i(const float (&f)[16]) {
  // exact: all addends are small integers
  float s0 = ((f[0] + f[1]) + (f[2] + f[3])) + ((f[4] + f[5]) + (f[6] + f[7]));
  float s1 = ((f[8] + f[9]) + (f[10] + f[11])) + ((f[12] + f[13]) + (f[14] + f[15]));
  return ((int)(s0 + s1)) & 1;
}

// Exact numpy-pipeline evaluation of candidate kk (R2..R6-verified).
template <bool EMIT>
__device__ __forceinline__ float eval_k(int kk, const float (&x)[16],
                                        const float (&xh)[16], float a,
                                        float (&y)[16]) {
#pragma clang fp contract(off)
  float f[16], dd[16];
#pragma unroll
  for (int j = 0; j < 16; ++j) {
    float c = (float)__builtin_popcount(kk & mk.m[j]);
    float x2 = __builtin_fmaf(c, -0.5f, xh[j]);  // == fl(xh - c/2)
    float fj = __builtin_rintf(x2);
    f[j] = fj;
    dd[j] = x2 - fj;                             // exact
  }
  const int par = parity16i(f);

  // first-occurrence argmax of |dd| -> onehot (left wins ties)
  float tv[16];
  int ti[16];
#pragma unroll
  for (int j = 0; j < 16; ++j) { tv[j] = __builtin_fabsf(dd[j]); ti[j] = 1 << j; }
#pragma unroll
  for (int w = 8; w >= 1; w >>= 1) {
#pragma unroll
    for (int j = 0; j < w; ++j) {
      bool L = tv[2 * j] >= tv[2 * j + 1];
      tv[j] = L ? tv[2 * j] : tv[2 * j + 1];
      ti[j] = L ? ti[2 * j] : ti[2 * j + 1];
    }
  }
  const int ohm = par ? ti[0] : 0;   // patch mask (0 when parity even)

  float sq[16];
#pragma unroll
  for (int j = 0; j < 16; ++j) {
    float c  = (float)__builtin_popcount(kk & mk.m[j]);
    float X  = __builtin_fmaf(2.0f, f[j], c);          // exact int
    float s2 = __builtin_copysignf(2.0f, dd[j]);       // corr direction
    float bitf = (float)((ohm >> j) & 1);
    float Xp = __builtin_fmaf(bitf, s2, X);            // exact int
    float e  = Xp - x[j];                              // single rounding
    sq[j] = e * e;
    if (EMIT) y[j] = Xp * a;
  }
  float r0 = sq[0] + sq[8],  r1 = sq[1] + sq[9];
  float r2 = sq[2] + sq[10], r3 = sq[3] + sq[11];
  float r4 = sq[4] + sq[12], r5 = sq[5] + sq[13];
  float r6 = sq[6] + sq[14], r7 = sq[7] + sq[15];
  return ((r0 + r1) + (r2 + r3)) + ((r4 + r5) + (r6 + r7));
}

__global__ __launch_bounds__(256, 4) void bw_quant_kernel(
    const float* __restrict__ x_in,
    const float* __restrict__ C_rep,   // unused (constexpr codebook)
    const float* __restrict__ a_ptr,
    float* __restrict__ y_out,
    int n_rows)
{
#pragma clang fp contract(off)
  const int row = blockIdx.x * 256 + threadIdx.x;
  if (row >= n_rows) return;

  const float a = a_ptr[0];

  float x[16], xh[16];
  {
    const float4* xr4 = reinterpret_cast<const float4*>(x_in + (size_t)row * 16);
#pragma unroll
    for (int q = 0; q < 4; ++q) {
      float4 v = xr4[q];
      x[q * 4 + 0] = v.x / a;
      x[q * 4 + 1] = v.y / a;
      x[q * 4 + 2] = v.z / a;
      x[q * 4 + 3] = v.w / a;
    }
#pragma unroll
    for (int j = 0; j < 16; ++j) xh[j] = x[j] * 0.5f;  // exact
  }

  // P0/P1: per-coordinate parities of rint(xh) / rint(xh - 0.5)
  int P0 = 0, P1 = 0;
#pragma unroll
  for (int j = 0; j < 16; ++j) {
    float t0 = __builtin_rintf(xh[j]);
    float t1 = __builtin_rintf(xh[j] - 0.5f);
    P0 |= ((int)t0 & 1) << j;
    P1 |= ((int)t1 & 1) << j;
  }

  // -------- pass 1: surrogate ranking (rolled), keep stable top-3 ---------
  float b1 = __builtin_inff(), b2 = b1, b3 = b1;
  int k1 = 0, k2 = 0, k3 = 0;

#pragma unroll 1
  for (int k = 0; k < 32; ++k) {
    const KRow& r = ktab.r[k];          // uniform k -> scalar loads
    float dd[16];
#pragma unroll
    for (int j = 0; j < 16; ++j) {
      float x2 = xh[j] - r.ch[j];
      float g = __builtin_rintf(x2);
      dd[j] = x2 - g;
    }

    // ssum = sum dd^2 : 4 parallel fma chains (surrogate precision)
    float s0 = __builtin_fmaf(dd[0], dd[0], __builtin_fmaf(dd[1], dd[1],
               __builtin_fmaf(dd[2], dd[2], dd[3] * dd[3])));
    float s1 = __builtin_fmaf(dd[4], dd[4], __builtin_fmaf(dd[5], dd[5],
               __builtin_fmaf(dd[6], dd[6], dd[7] * dd[7])));
    float s2 = __builtin_fmaf(dd[8], dd[8], __builtin_fmaf(dd[9], dd[9],
               __builtin_fmaf(dd[10], dd[10], dd[11] * dd[11])));
    float s3 = __builtin_fmaf(dd[12], dd[12], __builtin_fmaf(dd[13], dd[13],
               __builtin_fmaf(dd[14], dd[14], dd[15] * dd[15])));
    float s = (s0 + s1) + (s2 + s3);

    // mx = max |dd| via v_max3 triples (abs folds as VOP3 src modifiers)
    float t0 = __builtin_fmaxf(__builtin_fmaxf(__builtin_fabsf(dd[0]),  __builtin_fabsf(dd[1])),  __builtin_fabsf(dd[2]));
    float t1 = __builtin_fmaxf(__builtin_fmaxf(__builtin_fabsf(dd[3]),  __builtin_fabsf(dd[4])),  __builtin_fabsf(dd[5]));
    float t2 = __builtin_fmaxf(__builtin_fmaxf(__builtin_fabsf(dd[6]),  __builtin_fabsf(dd[7])),  __builtin_fabsf(dd[8]));
    float t3 = __builtin_fmaxf(__builtin_fmaxf(__builtin_fabsf(dd[9]),  __builtin_fabsf(dd[10])), __builtin_fabsf(dd[11]));
    float t4 = __builtin_fmaxf(__builtin_fmaxf(__builtin_fabsf(dd[12]), __builtin_fabsf(dd[13])), __builtin_fabsf(dd[14]));
    float mx = __builtin_fmaxf(__builtin_fmaxf(__builtin_fmaxf(t0, t1), t2),
                               __builtin_fmaxf(__builtin_fmaxf(t3, t4), __builtin_fabsf(dd[15])));

    // mask parity (R5/R6-validated): bfi + popcount + add + and
    unsigned sel = (r.odd & (unsigned)P1) | (~r.odd & (unsigned)P0);
    int cnt = __builtin_popcount(sel) + (int)r.par2;
    float spen = s + __builtin_fmaf(-2.0f, mx, 1.0f);
    float dtil = (cnt & 1) ? spen : s;

    // stable top-3 insert (strict <: earlier k wins ties)
    bool lt1 = dtil < b1, lt2 = dtil < b2, lt3 = dtil < b3;
    float nb3 = lt3 ? (lt2 ? b2 : dtil) : b3;  int nk3 = lt3 ? (lt2 ? k2 : k) : k3;
    float nb2 = lt2 ? (lt1 ? b1 : dtil) : b2;  int nk2 = lt2 ? (lt1 ? k1 : k) : k2;
    b3 = nb3; k3 = nk3;
    b2 = nb2; k2 = nk2;
    b1 = lt1 ? dtil : b1;  k1 = lt1 ? k : k1;
  }

  // -------- pass 2: exact evaluation of the 3 survivors -------------------
  float ydummy[16];
  float D1 = eval_k<false>(k1, x, xh, a, ydummy);
  float D2 = eval_k<false>(k2, x, xh, a, ydummy);
  float D3 = eval_k<false>(k3, x, xh, a, ydummy);

  // lexicographic (D, k) == numpy first-min over the candidate set
  bool c2 = (D2 < D1) || (D2 == D1 && k2 < k1);
  float Db = c2 ? D2 : D1;
  int kb = c2 ? k2 : k1;
  bool c3 = (D3 < Db) || (D3 == Db && k3 < kb);
  kb = c3 ? k3 : kb;

  // -------- emit: exact re-eval of the winner -----------------------------
  float y[16];
  (void)eval_k<true>(kb, x, xh, a, y);

  float4* yr4 = reinterpret_cast<float4*>(y_out + (size_t)row * 16);
#pragma unroll
  for (int q = 0; q < 4; ++q) {
    float4 v;
    v.x = y[q * 4 + 0]; v.y = y[q * 4 + 1];
    v.z = y[q * 4 + 2]; v.w = y[q * 4 + 3];
    yr4[q] = v;
  }
}

extern "C" void kernel_launch(void* const* d_in, const int* in_sizes, int n_in,
                              void* d_out, int out_size, void* d_ws, size_t ws_size,
                              hipStream_t stream) {
  const float* x_in  = (const float*)d_in[0];
  const float* C_rep = (const float*)d_in[1];
  const float* a_ptr = (const float*)d_in[2];
  float* y_out = (float*)d_out;

  const int n_rows = in_sizes[0] / 16;
  const int block = 256;
  const int grid = (n_rows + block - 1) / block;
  bw_quant_kernel<<<grid, block, 0, stream>>>(x_in, C_rep, a_ptr, y_out, n_rows);
}